// Round 5
// baseline (148.499 us; speedup 1.0000x reference)
//
#include <hip/hip_runtime.h>

// FwFM second-order interaction.
// Identity: v^T S v == v^T W v for S = 0.5(W+W^T), diag(S) = diag(W), so
//   out[b,d] = sum_{k<l} 0.5*(W[k,l]+W[l,k]) * x[k,b,d]*x[l,b,d]   (741 pairs, K=39)
//
// Shapes: x [39, 8192, 64] f32, W [39,39] f32, out [8192,64] f32.
// Memory floor: ~84 MB traffic -> ~13.6 us at 6.3 TB/s achievable.
// NOTE: dur_us carries ~89 us of harness reset (327 MB ws poison + input
// restore), measured via R1 (fwfm=84 us profiled, total=172.7).
//
// R5 = R4 with the compile fix: __builtin_nontemporal_* requires a NATIVE
// vector type (ext_vector_type), not HIP_vector_type float4.
//  - float4 per thread: 39 x global_load_dwordx4 = 1 KB/wave/instr (sweet spot).
//  - nontemporal load/store: x and out are pure streams, keep them out of L2.
//  - waves_per_eu(2,2): ~176 VGPR body gets a 256-reg budget -> no spill
//    possible (R1 failure mode). 512 blocks = 2 blocks/CU, 8 waves/CU;
//    in-flight bytes 312 KB/CU >> BWxlatency ~12 KB -> latency hiding OK.

#define KF 39
#define NPAIR (KF * (KF - 1) / 2)   // 741
#define NELEM (8192 * 64)           // B*D = 524288 output elements
#define NV4   (NELEM / 4)           // float4 elements per field = 131072

typedef float f32x4 __attribute__((ext_vector_type(4)));

// Tiny precompute: c[p] = 0.5*(W[k,l]+W[l,k]) for l<k, p = k(k-1)/2 + l.
// Contiguous pair order -> main kernel's uniform reads batch into s_load_dwordx16.
__global__ void fwfm_coef_kernel(const float* __restrict__ W, float* __restrict__ c) {
    const int t = blockIdx.x * 256 + threadIdx.x;   // over K*K = 1521
    if (t >= KF * KF) return;
    const int k = t / KF;
    const int l = t - k * KF;
    if (l < k) {
        c[(k * (k - 1)) / 2 + l] = 0.5f * (W[k * KF + l] + W[l * KF + k]);
    }
}

__global__ __attribute__((amdgpu_flat_work_group_size(256, 256), amdgpu_waves_per_eu(2, 2)))
void fwfm_kernel(const float* __restrict__ x,
                 const float* __restrict__ c,
                 float* __restrict__ out) {
    const int n = blockIdx.x * 256 + threadIdx.x;   // float4 index in [0, NV4)

    const f32x4* __restrict__ x4 = reinterpret_cast<const f32x4*>(x);

    // 39 coalesced nontemporal dwordx4 loads; all independent, issued up front.
    f32x4 v[KF];
#pragma unroll
    for (int k = 0; k < KF; ++k) {
        v[k] = __builtin_nontemporal_load(&x4[(size_t)k * NV4 + n]);
    }

    // Pair loop in coefficient order (p sequential -> batched s_loads).
    // c is wave-uniform: the single SGPR operand of v_fmac_f32.
    // Four independent chains for ILP.
    f32x4 acc = {0.f, 0.f, 0.f, 0.f};
    int p = 0;
#pragma unroll
    for (int k = 1; k < KF; ++k) {
        f32x4 w = {0.f, 0.f, 0.f, 0.f};
#pragma unroll
        for (int l = 0; l < k; ++l) {
            const float cc = c[p++];
            w.x = fmaf(cc, v[l].x, w.x);
            w.y = fmaf(cc, v[l].y, w.y);
            w.z = fmaf(cc, v[l].z, w.z);
            w.w = fmaf(cc, v[l].w, w.w);
        }
        acc.x = fmaf(v[k].x, w.x, acc.x);
        acc.y = fmaf(v[k].y, w.y, acc.y);
        acc.z = fmaf(v[k].z, w.z, acc.z);
        acc.w = fmaf(v[k].w, w.w, acc.w);
    }

    // 0.5 already folded into c.
    __builtin_nontemporal_store(acc, &reinterpret_cast<f32x4*>(out)[n]);
}

extern "C" void kernel_launch(void* const* d_in, const int* in_sizes, int n_in,
                              void* d_out, int out_size, void* d_ws, size_t ws_size,
                              hipStream_t stream) {
    const float* x = (const float*)d_in[0];          // [39, 8192, 64]
    const float* W = (const float*)d_in[1];          // [39, 39]
    float* out = (float*)d_out;                      // [8192, 64]
    float* coef = (float*)d_ws;                      // 741 floats of scratch

    fwfm_coef_kernel<<<(KF * KF + 255) / 256, 256, 0, stream>>>(W, coef);
    fwfm_kernel<<<NV4 / 256, 256, 0, stream>>>(x, coef, out);
}

// Round 6
// 121.998 us; speedup vs baseline: 1.2172x; 1.2172x over previous
//
#include <hip/hip_runtime.h>

// FwFM second-order interaction.
// Identity: v^T S v == v^T W v for S = 0.5(W+W^T), diag(S) = diag(W), so
//   out[b,d] = sum_{k<l} 0.5*(W[k,l]+W[l,k]) * x[k,b,d]*x[l,b,d]   (741 pairs, K=39)
//
// Shapes: x [39, 8192, 64] f32, W [39,39] f32, out [8192,64] f32.
// Memory floor: ~84 MB traffic -> ~13.6 us at 6.3 TB/s achievable.
// dur_us carries ~77-90 us of harness reset (327 MB ws poison at ~49 us +
// 84 MB input restore) — visible as fillBufferAligned dispatches.
//
// R6: kill the spill. Empirical budget rule on this toolchain (fit from
// R1: launch_bounds(256,4)->64 VGPR and R5: waves_per_eu(2,2)->128 VGPR):
//     arch-VGPR budget = 256 / min_waves_per_eu     (NOT 512/min)
// R5's float4 body needed ~185 regs vs 128 budget -> 58 dwords/thread spill
// (= the 30.7 MB WRITE_SIZE excess, exactly). R2/R3 were also spill-bound.
//   - float2/thread: body ~100 regs < 128 budget -> no spill.
//   - waves_per_eu(2,2): max=2 stops the RA squeezing to 64 for occupancy
//     (R1 failure mode). 2 waves/EU = 8 waves/CU; in-flight 160 KB/CU >>
//     BW*latency ~10 KB -> latency hiding OK.
//   - plain loads (no nontemporal): L2/L3 already serve part of x from the
//     harness restore copy (R5 FETCH 52 MB < 82 MB ideal).

#define KF 39
#define NPAIR (KF * (KF - 1) / 2)   // 741
#define NELEM (8192 * 64)           // B*D = 524288 output elements
#define NV2   (NELEM / 2)           // float2 elements per field = 262144

typedef float f32x2 __attribute__((ext_vector_type(2)));

// Tiny precompute: c[p] = 0.5*(W[k,l]+W[l,k]) for l<k, p = k(k-1)/2 + l.
// Contiguous pair order -> main kernel's uniform reads batch into s_load_dwordx16.
__global__ void fwfm_coef_kernel(const float* __restrict__ W, float* __restrict__ c) {
    const int t = blockIdx.x * 256 + threadIdx.x;   // over K*K = 1521
    if (t >= KF * KF) return;
    const int k = t / KF;
    const int l = t - k * KF;
    if (l < k) {
        c[(k * (k - 1)) / 2 + l] = 0.5f * (W[k * KF + l] + W[l * KF + k]);
    }
}

__global__ __attribute__((amdgpu_flat_work_group_size(256, 256), amdgpu_waves_per_eu(2, 2)))
void fwfm_kernel(const float* __restrict__ x,
                 const float* __restrict__ c,
                 float* __restrict__ out) {
    const int n = blockIdx.x * 256 + threadIdx.x;   // float2 index in [0, NV2)

    const f32x2* __restrict__ x2 = reinterpret_cast<const f32x2*>(x);

    // 39 coalesced dwordx2 loads (512 B/wave/instr); all independent.
    f32x2 v[KF];
#pragma unroll
    for (int k = 0; k < KF; ++k) {
        v[k] = x2[(size_t)k * NV2 + n];
    }

    // Pair loop in coefficient order (p sequential -> batched s_loads).
    // c is wave-uniform: the single SGPR operand of v_fmac_f32.
    // Two independent chains for ILP.
    f32x2 acc = {0.f, 0.f};
    int p = 0;
#pragma unroll
    for (int k = 1; k < KF; ++k) {
        f32x2 w = {0.f, 0.f};
#pragma unroll
        for (int l = 0; l < k; ++l) {
            const float cc = c[p++];
            w.x = fmaf(cc, v[l].x, w.x);
            w.y = fmaf(cc, v[l].y, w.y);
        }
        acc.x = fmaf(v[k].x, w.x, acc.x);
        acc.y = fmaf(v[k].y, w.y, acc.y);
    }

    // 0.5 already folded into c.
    reinterpret_cast<f32x2*>(out)[n] = acc;
}

extern "C" void kernel_launch(void* const* d_in, const int* in_sizes, int n_in,
                              void* d_out, int out_size, void* d_ws, size_t ws_size,
                              hipStream_t stream) {
    const float* x = (const float*)d_in[0];          // [39, 8192, 64]
    const float* W = (const float*)d_in[1];          // [39, 39]
    float* out = (float*)d_out;                      // [8192, 64]
    float* coef = (float*)d_ws;                      // 741 floats of scratch

    fwfm_coef_kernel<<<(KF * KF + 255) / 256, 256, 0, stream>>>(W, coef);
    fwfm_kernel<<<NV2 / 256, 256, 0, stream>>>(x, coef, out);
}